// Round 1
// baseline (635.851 us; speedup 1.0000x reference)
//
#include <hip/hip_runtime.h>
#include <math.h>

#define B_ 8
#define N_ 4096
#define D_ 1024
#define E_ 64
#define T_ 128
#define H_ 1024

// ---------------------------------------------------------------------------
// GEMM NT: C[m,n] = sum_k A[m,k] * B[n,k]   (both K-contiguous, K=1024)
// tile 128x128x32, 256 threads, 8x8 per thread. Optional batch + split-K.
// ---------------------------------------------------------------------------
__global__ __launch_bounds__(256) void gemm_nt(
    const float* __restrict__ A, const float* __restrict__ Bm, float* __restrict__ C,
    int ldc, long sA, long sB, long sC, int kPer, int nK, long sPart)
{
  const int batch = blockIdx.z / nK;
  const int kc    = blockIdx.z % nK;
  A  += (long)batch * sA;
  Bm += (long)batch * sB;
  C  += (long)batch * sC + (long)kc * sPart;
  const int m0 = blockIdx.y * 128;
  const int n0 = blockIdx.x * 128;
  const int tid = threadIdx.x;
  const int tx = tid & 15, ty = tid >> 4;

  __shared__ __align__(16) float As[32][132];
  __shared__ __align__(16) float Bs[32][132];

  float acc[8][8];
#pragma unroll
  for (int i = 0; i < 8; ++i)
#pragma unroll
    for (int j = 0; j < 8; ++j) acc[i][j] = 0.f;

  const int kEnd = (kc + 1) * kPer;
  for (int k0 = kc * kPer; k0 < kEnd; k0 += 32) {
#pragma unroll
    for (int l = 0; l < 4; ++l) {
      int f = tid + l * 256;
      int r = f >> 3, c4 = f & 7;
      float4 v = *(const float4*)(A + (long)(m0 + r) * 1024 + k0 + c4 * 4);
      As[c4*4+0][r] = v.x; As[c4*4+1][r] = v.y; As[c4*4+2][r] = v.z; As[c4*4+3][r] = v.w;
      float4 w = *(const float4*)(Bm + (long)(n0 + r) * 1024 + k0 + c4 * 4);
      Bs[c4*4+0][r] = w.x; Bs[c4*4+1][r] = w.y; Bs[c4*4+2][r] = w.z; Bs[c4*4+3][r] = w.w;
    }
    __syncthreads();
#pragma unroll
    for (int k = 0; k < 32; ++k) {
      float a[8], b[8];
      *(float4*)&a[0] = *(const float4*)&As[k][ty*8];
      *(float4*)&a[4] = *(const float4*)&As[k][ty*8+4];
      *(float4*)&b[0] = *(const float4*)&Bs[k][tx*8];
      *(float4*)&b[4] = *(const float4*)&Bs[k][tx*8+4];
#pragma unroll
      for (int i = 0; i < 8; ++i)
#pragma unroll
        for (int j = 0; j < 8; ++j)
          acc[i][j] = fmaf(a[i], b[j], acc[i][j]);
    }
    __syncthreads();
  }
#pragma unroll
  for (int i = 0; i < 8; ++i) {
    float* Cr = C + (long)(m0 + ty*8 + i) * ldc + n0 + tx*8;
    *(float4*)Cr       = make_float4(acc[i][0], acc[i][1], acc[i][2], acc[i][3]);
    *(float4*)(Cr + 4) = make_float4(acc[i][4], acc[i][5], acc[i][6], acc[i][7]);
  }
}

// ---------------------------------------------------------------------------
// slots (split-K over N): Part[chunk][b][t][d] = sum_{n in chunk} DW[b,n,t]*X[b,n,d]
// ---------------------------------------------------------------------------
__global__ __launch_bounds__(256) void gemm_slots(
    const float* __restrict__ DW, const float* __restrict__ X, float* __restrict__ Part)
{
  const int b     = blockIdx.z >> 3;
  const int chunk = blockIdx.z & 7;
  const int d0 = blockIdx.x * 128;
  const float* A  = DW + (long)b * N_ * T_;
  const float* Bx = X  + (long)b * N_ * D_;
  float* Cp = Part + (long)chunk * (B_ * T_ * D_) + (long)b * T_ * D_;
  const int tid = threadIdx.x;
  const int tx = tid & 15, ty = tid >> 4;

  __shared__ __align__(16) float As[32][132];
  __shared__ __align__(16) float Bs[32][132];

  float acc[8][8];
#pragma unroll
  for (int i = 0; i < 8; ++i)
#pragma unroll
    for (int j = 0; j < 8; ++j) acc[i][j] = 0.f;

  const int nBase = chunk * 512;
  for (int k0 = 0; k0 < 512; k0 += 32) {
#pragma unroll
    for (int l = 0; l < 4; ++l) {
      int f = tid + l * 256;
      int r = f >> 5, c4 = f & 31;
      *(float4*)&As[r][c4*4] = *(const float4*)(A  + (long)(nBase + k0 + r) * T_ + c4 * 4);
      *(float4*)&Bs[r][c4*4] = *(const float4*)(Bx + (long)(nBase + k0 + r) * D_ + d0 + c4 * 4);
    }
    __syncthreads();
#pragma unroll
    for (int k = 0; k < 32; ++k) {
      float a[8], b[8];
      *(float4*)&a[0] = *(const float4*)&As[k][ty*8];
      *(float4*)&a[4] = *(const float4*)&As[k][ty*8+4];
      *(float4*)&b[0] = *(const float4*)&Bs[k][tx*8];
      *(float4*)&b[4] = *(const float4*)&Bs[k][tx*8+4];
#pragma unroll
      for (int i = 0; i < 8; ++i)
#pragma unroll
        for (int j = 0; j < 8; ++j)
          acc[i][j] = fmaf(a[i], b[j], acc[i][j]);
    }
    __syncthreads();
  }
#pragma unroll
  for (int i = 0; i < 8; ++i) {
    float* Cr = Cp + (long)(ty*8 + i) * D_ + d0 + tx*8;
    *(float4*)Cr       = make_float4(acc[i][0], acc[i][1], acc[i][2], acc[i][3]);
    *(float4*)(Cr + 4) = make_float4(acc[i][4], acc[i][5], acc[i][6], acc[i][7]);
  }
}

__global__ void reduce_k(const float* __restrict__ Part, float* __restrict__ Out, int nch)
{
  int idx = blockIdx.x * 256 + threadIdx.x;   // 1,048,576 total
  float s = 0.f;
  for (int c = 0; c < nch; ++c) s += Part[(long)c * 1048576 + idx];
  Out[idx] = s;
}

// ---------------------------------------------------------------------------
// per-expert MLP layer: Out[m,h] = act( sum_k A[m,k]*W[e,h,k] + bias[e,h] )
// m = b*2+s (16 rows), tile 16 x 256h x 32k. Rows live at b*T*1024 + (e*2+s)*1024.
// ---------------------------------------------------------------------------
template<int GELU>
__global__ __launch_bounds__(256) void expert_gemm(
    const float* __restrict__ Abase, const float* __restrict__ W,
    const float* __restrict__ bias, float* __restrict__ Out)
{
  const int e  = blockIdx.y;
  const int h0 = blockIdx.x * 256;
  const int tid = threadIdx.x;
  const int hq = tid & 63;     // h4 = hq*4
  const int mq = tid >> 6;     // m4 = mq*4

  __shared__ __align__(16) float Ws[32][260];
  __shared__ __align__(16) float As[32][20];

  float acc[4][4];
#pragma unroll
  for (int i = 0; i < 4; ++i)
#pragma unroll
    for (int j = 0; j < 4; ++j) acc[i][j] = 0.f;

  for (int k0 = 0; k0 < 1024; k0 += 32) {
    if (tid < 128) {
      int r = tid >> 3, c4 = tid & 7;
      const float* Ar = Abase + (long)(r >> 1) * (T_ * 1024) + (long)(e * 2 + (r & 1)) * 1024;
      float4 v = *(const float4*)(Ar + k0 + c4 * 4);
      As[c4*4+0][r] = v.x; As[c4*4+1][r] = v.y; As[c4*4+2][r] = v.z; As[c4*4+3][r] = v.w;
    }
#pragma unroll
    for (int l = 0; l < 8; ++l) {
      int f = tid + l * 256;
      int hr = f >> 3, c4 = f & 7;
      float4 v = *(const float4*)(W + ((long)e * 1024 + h0 + hr) * 1024 + k0 + c4 * 4);
      Ws[c4*4+0][hr] = v.x; Ws[c4*4+1][hr] = v.y; Ws[c4*4+2][hr] = v.z; Ws[c4*4+3][hr] = v.w;
    }
    __syncthreads();
#pragma unroll
    for (int k = 0; k < 32; ++k) {
      float4 a = *(const float4*)&As[k][mq*4];
      float4 w = *(const float4*)&Ws[k][hq*4];
      float av[4] = {a.x, a.y, a.z, a.w};
      float wv[4] = {w.x, w.y, w.z, w.w};
#pragma unroll
      for (int i = 0; i < 4; ++i)
#pragma unroll
        for (int j = 0; j < 4; ++j)
          acc[i][j] = fmaf(av[i], wv[j], acc[i][j]);
    }
    __syncthreads();
  }

  const float4 bv = *(const float4*)(bias + (long)e * 1024 + h0 + hq * 4);
  float bb[4] = {bv.x, bv.y, bv.z, bv.w};
#pragma unroll
  for (int i = 0; i < 4; ++i) {
    int m = mq * 4 + i;
    float o4[4];
#pragma unroll
    for (int j = 0; j < 4; ++j) {
      float xg = acc[i][j] + bb[j];
      if (GELU) {
        float x3 = xg * xg * xg;
        xg = 0.5f * xg * (1.f + tanhf(0.7978845608028654f * (xg + 0.044715f * x3)));
      }
      o4[j] = xg;
    }
    float* Or = Out + (long)(m >> 1) * (T_ * 1024) + (long)(e * 2 + (m & 1)) * 1024 + h0 + hq * 4;
    *(float4*)Or = make_float4(o4[0], o4[1], o4[2], o4[3]);
  }
}

// ---------------------------------------------------------------------------
// dispatch softmax over tokens (axis N), 3 stages
// ---------------------------------------------------------------------------
__global__ __launch_bounds__(256) void disp_partial(const float* __restrict__ L,
    float* __restrict__ redM, float* __restrict__ redS)
{
  const int chunk = blockIdx.x;      // 0..31
  const int b     = blockIdx.y;      // 0..7
  const int t    = threadIdx.x & 127;
  const int half = threadIdx.x >> 7;
  const float* Lb = L + (long)b * N_ * T_;
  float m = -1e30f, s = 0.f;
  for (int i = 0; i < 64; ++i) {
    int n = chunk * 128 + i * 2 + half;
    float v = Lb[(long)n * T_ + t];
    if (v > m) { s = s * expf(m - v) + 1.f; m = v; }
    else       { s += expf(v - m); }
  }
  __shared__ float sm[128], ss[128];
  if (half) { sm[t] = m; ss[t] = s; }
  __syncthreads();
  if (!half) {
    float m2 = sm[t], s2 = ss[t];
    float nm = fmaxf(m, m2);
    float ns = s * expf(m - nm) + s2 * expf(m2 - nm);
    redM[((long)b * 32 + chunk) * 128 + t] = nm;
    redS[((long)b * 32 + chunk) * 128 + t] = ns;
  }
}

__global__ void disp_final(const float* __restrict__ redM, const float* __restrict__ redS,
                           float* __restrict__ Mf, float* __restrict__ Zf)
{
  int idx = blockIdx.x * 256 + threadIdx.x;   // 1024 total
  int b = idx >> 7, t = idx & 127;
  float m = -1e30f, s = 0.f;
  for (int c = 0; c < 32; ++c) {
    float mc = redM[((long)b * 32 + c) * 128 + t];
    float sc = redS[((long)b * 32 + c) * 128 + t];
    float nm = fmaxf(m, mc);
    s = s * expf(m - nm) + sc * expf(mc - nm);
    m = nm;
  }
  Mf[idx] = m;
  Zf[idx] = 1.f / s;
}

__global__ void disp_write(const float* __restrict__ L, const float* __restrict__ Mf,
                           const float* __restrict__ Zf, float* __restrict__ DW)
{
  int i4 = blockIdx.x * 256 + threadIdx.x;   // 0..1048575
  long idx = (long)i4 * 4;
  int b  = (int)(idx >> 19);                  // / (N*T)
  int t0 = (int)(idx & 127);
  int base = b * 128 + t0;
  float4 v = *(const float4*)(L + idx);
  float4 o;
  o.x = expf(v.x - Mf[base+0]) * Zf[base+0];
  o.y = expf(v.y - Mf[base+1]) * Zf[base+1];
  o.z = expf(v.z - Mf[base+2]) * Zf[base+2];
  o.w = expf(v.w - Mf[base+3]) * Zf[base+3];
  *(float4*)(DW + idx) = o;
}

// combine softmax over slots (axis T=128), in-place, one wave per row
__global__ __launch_bounds__(256) void combine_softmax(float* __restrict__ L)
{
  const int row  = blockIdx.x * 4 + (threadIdx.x >> 6);   // B*N rows
  const int lane = threadIdx.x & 63;
  float* Lr = L + (long)row * T_;
  float v0 = Lr[lane], v1 = Lr[lane + 64];
  float m = fmaxf(v0, v1);
#pragma unroll
  for (int o = 32; o; o >>= 1) m = fmaxf(m, __shfl_xor(m, o));
  float e0 = expf(v0 - m), e1 = expf(v1 - m);
  float s = e0 + e1;
#pragma unroll
  for (int o = 32; o; o >>= 1) s += __shfl_xor(s, o);
  float inv = 1.f / s;
  Lr[lane]      = e0 * inv;
  Lr[lane + 64] = e1 * inv;
}

// ---------------------------------------------------------------------------
// final: Out[b,n,o] = sum_t CW[b,n,t] * P[b,t,o] + out_b[o]   (K = T = 128)
// ---------------------------------------------------------------------------
__global__ __launch_bounds__(256) void gemm_combine(
    const float* __restrict__ CW, const float* __restrict__ P,
    const float* __restrict__ ob, float* __restrict__ Outp)
{
  const int b  = blockIdx.z;
  const int m0 = blockIdx.y * 128;   // token tile
  const int n0 = blockIdx.x * 128;   // output-dim tile
  const float* A  = CW + (long)b * N_ * T_;
  const float* Bp = P  + (long)b * T_ * D_;
  const int tid = threadIdx.x;
  const int tx = tid & 15, ty = tid >> 4;

  __shared__ __align__(16) float As[32][132];
  __shared__ __align__(16) float Bs[32][132];

  float acc[8][8];
#pragma unroll
  for (int i = 0; i < 8; ++i)
#pragma unroll
    for (int j = 0; j < 8; ++j) acc[i][j] = 0.f;

  for (int k0 = 0; k0 < 128; k0 += 32) {
#pragma unroll
    for (int l = 0; l < 4; ++l) {
      int f = tid + l * 256;
      { int r = f >> 3, c4 = f & 7;
        float4 v = *(const float4*)(A + (long)(m0 + r) * T_ + k0 + c4 * 4);
        As[c4*4+0][r] = v.x; As[c4*4+1][r] = v.y; As[c4*4+2][r] = v.z; As[c4*4+3][r] = v.w; }
      { int r = f >> 5, c4 = f & 31;
        *(float4*)&Bs[r][c4*4] = *(const float4*)(Bp + (long)(k0 + r) * D_ + n0 + c4 * 4); }
    }
    __syncthreads();
#pragma unroll
    for (int k = 0; k < 32; ++k) {
      float a[8], bb[8];
      *(float4*)&a[0]  = *(const float4*)&As[k][ty*8];
      *(float4*)&a[4]  = *(const float4*)&As[k][ty*8+4];
      *(float4*)&bb[0] = *(const float4*)&Bs[k][tx*8];
      *(float4*)&bb[4] = *(const float4*)&Bs[k][tx*8+4];
#pragma unroll
      for (int i = 0; i < 8; ++i)
#pragma unroll
        for (int j = 0; j < 8; ++j)
          acc[i][j] = fmaf(a[i], bb[j], acc[i][j]);
    }
    __syncthreads();
  }
  float4 b0 = *(const float4*)(ob + n0 + tx*8);
  float4 b1 = *(const float4*)(ob + n0 + tx*8 + 4);
#pragma unroll
  for (int i = 0; i < 8; ++i) {
    float* Cr = Outp + (long)b * N_ * D_ + (long)(m0 + ty*8 + i) * D_ + n0 + tx*8;
    *(float4*)Cr       = make_float4(acc[i][0]+b0.x, acc[i][1]+b0.y, acc[i][2]+b0.z, acc[i][3]+b0.w);
    *(float4*)(Cr + 4) = make_float4(acc[i][4]+b1.x, acc[i][5]+b1.y, acc[i][6]+b1.z, acc[i][7]+b1.w);
  }
}

__global__ void write_aux(float* __restrict__ out) { out[(long)B_ * N_ * D_] = 0.f; }

// ---------------------------------------------------------------------------
extern "C" void kernel_launch(void* const* d_in, const int* in_sizes, int n_in,
                              void* d_out, int out_size, void* d_ws, size_t ws_size,
                              hipStream_t stream)
{
  const float* x     = (const float*)d_in[0];
  const float* phi_w = (const float*)d_in[1];
  const float* fc1_w = (const float*)d_in[2];
  const float* fc1_b = (const float*)d_in[3];
  const float* fc2_w = (const float*)d_in[4];
  const float* fc2_b = (const float*)d_in[5];
  const float* out_w = (const float*)d_in[6];
  const float* out_b = (const float*)d_in[7];
  float* out = (float*)d_out;

  float* ws     = (float*)d_ws;
  float* logits = ws;                       // 4,194,304 (becomes combine_w in place)
  float* dispw  = logits + 4194304;         // 4,194,304
  float* redM   = dispw  + 4194304;         // 32,768
  float* redS   = redM   + 32768;           // 32,768
  float* Mf     = redS   + 32768;           // 1,024
  float* Zf     = Mf     + 1024;            // 1,024
  float* slots  = Zf     + 1024;            // 1,048,576
  float* hbuf   = slots  + 1048576;         // 1,048,576
  float* outsb  = hbuf   + 1048576;         // 1,048,576
  float* proj   = outsb  + 1048576;         // 1,048,576   (~50.6 MB total)
  float* part   = out;                      // split-K scratch in d_out (dead until gemm_combine)

  // 1) logits = x @ phi_w^T   (M=32768, N=128, K=1024)
  gemm_nt<<<dim3(1, 256, 1), 256, 0, stream>>>(x, phi_w, logits, 128, 0, 0, 0, 1024, 1, 0);
  // 2) dispatch softmax over tokens
  disp_partial<<<dim3(32, 8), 256, 0, stream>>>(logits, redM, redS);
  disp_final<<<dim3(4), 256, 0, stream>>>(redM, redS, Mf, Zf);
  disp_write<<<dim3(4096), 256, 0, stream>>>(logits, Mf, Zf, dispw);
  // 3) combine softmax over slots (in place -> logits becomes combine_w)
  combine_softmax<<<dim3(8192), 256, 0, stream>>>(logits);
  // 4) slots = dispatch_w^T @ x  (per b, split-K x8)
  gemm_slots<<<dim3(8, 1, 64), 256, 0, stream>>>(dispw, x, part);
  reduce_k<<<dim3(4096), 256, 0, stream>>>(part, slots, 8);
  // 5) expert MLPs
  expert_gemm<1><<<dim3(4, 64), 256, 0, stream>>>(slots, fc1_w, fc1_b, hbuf);
  expert_gemm<0><<<dim3(4, 64), 256, 0, stream>>>(hbuf, fc2_w, fc2_b, outsb);
  // 6) proj = out_s @ out_w^T  (flat 1024x1024x1024, split-K x4)
  gemm_nt<<<dim3(8, 8, 4), 256, 0, stream>>>(outsb, out_w, part, 1024, 0, 0, 0, 256, 4, 1048576);
  reduce_k<<<dim3(4096), 256, 0, stream>>>(part, proj, 4);
  // 7) output = combine_w @ proj + out_b
  gemm_combine<<<dim3(8, 32, 8), 256, 0, stream>>>(logits, proj, out_b, out);
  write_aux<<<1, 1, 0, stream>>>(out);
}

// Round 2
// 344.079 us; speedup vs baseline: 1.8480x; 1.8480x over previous
//
#include <hip/hip_runtime.h>
#include <math.h>

#define B_ 8
#define N_ 4096
#define D_ 1024
#define E_ 64
#define T_ 128

using bf16   = __bf16;
using bf16x4 = __attribute__((ext_vector_type(4))) __bf16;
using bf16x8 = __attribute__((ext_vector_type(8))) __bf16;
using f32x4  = __attribute__((ext_vector_type(4))) float;

#define MFMA16(a, b, c) __builtin_amdgcn_mfma_f32_16x16x32_bf16(a, b, c, 0, 0, 0)
#define LDK 72

// fragment read from LDS tile stored [row][k] with row stride LDK (bf16):
// lane l reads 8 contiguous k at row (l&15), k-offset (l>>4)*8
__device__ __forceinline__ bf16x8 ldsfrag(const bf16* p) {
  const int lane = threadIdx.x & 63;
  return *(const bf16x8*)(p + (lane & 15) * LDK + (lane >> 4) * 8);
}

// ---------------------------------------------------------------------------
// convert phi_w (131072 f) and out_w (1048576 f) to bf16
// ---------------------------------------------------------------------------
__global__ void k_convert(const float* __restrict__ phi, const float* __restrict__ ow,
                          bf16* __restrict__ phi_bf, bf16* __restrict__ ow_bf)
{
  if (blockIdx.x < 128) {
    int i = blockIdx.x * 256 + threadIdx.x;        // 0..32767 float4s
    float4 v = ((const float4*)phi)[i];
    ((bf16x4*)phi_bf)[i] = (bf16x4){(bf16)v.x, (bf16)v.y, (bf16)v.z, (bf16)v.w};
  } else {
    int i = (blockIdx.x - 128) * 256 + threadIdx.x; // 0..262143
    float4 v = ((const float4*)ow)[i];
    ((bf16x4*)ow_bf)[i] = (bf16x4){(bf16)v.x, (bf16)v.y, (bf16)v.z, (bf16)v.w};
  }
}

// ---------------------------------------------------------------------------
// logits = x @ phi_bf^T  (M=32768, N=128, K=1024); also emits Xbf (x in bf16).
// BM=64, BN=128, BK=64, 4 waves (wave tile 32x64).
// ---------------------------------------------------------------------------
__global__ __launch_bounds__(256) void k_logits(
    const float* __restrict__ X, const bf16* __restrict__ Phi,
    float* __restrict__ L, bf16* __restrict__ Xbf)
{
  __shared__ bf16 As[64][LDK];
  __shared__ bf16 Bs[128][LDK];
  const int m0 = blockIdx.x * 64;
  const int tid = threadIdx.x;
  const int wave = tid >> 6, lane = tid & 63;
  const int wm = (wave >> 1) * 32;
  const int wn = (wave & 1) * 64;

  f32x4 acc[2][4];
#pragma unroll
  for (int i = 0; i < 2; ++i)
#pragma unroll
    for (int j = 0; j < 4; ++j) acc[i][j] = (f32x4){0.f, 0.f, 0.f, 0.f};

  const int ar = tid >> 2, ac = (tid & 3) * 16;
  const int br = tid >> 1, bc = (tid & 1) * 32;

  for (int k0 = 0; k0 < 1024; k0 += 64) {
    const float* xp = X + (long)(m0 + ar) * 1024 + k0 + ac;
    float4 v0 = *(const float4*)(xp + 0);
    float4 v1 = *(const float4*)(xp + 4);
    float4 v2 = *(const float4*)(xp + 8);
    float4 v3 = *(const float4*)(xp + 12);
    bf16x8 p0 = {(bf16)v0.x, (bf16)v0.y, (bf16)v0.z, (bf16)v0.w,
                 (bf16)v1.x, (bf16)v1.y, (bf16)v1.z, (bf16)v1.w};
    bf16x8 p1 = {(bf16)v2.x, (bf16)v2.y, (bf16)v2.z, (bf16)v2.w,
                 (bf16)v3.x, (bf16)v3.y, (bf16)v3.z, (bf16)v3.w};
    *(bf16x8*)&As[ar][ac]     = p0;
    *(bf16x8*)&As[ar][ac + 8] = p1;
    bf16* xo = Xbf + (long)(m0 + ar) * 1024 + k0 + ac;
    *(bf16x8*)xo       = p0;
    *(bf16x8*)(xo + 8) = p1;

    const bf16* pp = Phi + (long)br * 1024 + k0 + bc;
    *(bf16x8*)&Bs[br][bc + 0]  = *(const bf16x8*)(pp + 0);
    *(bf16x8*)&Bs[br][bc + 8]  = *(const bf16x8*)(pp + 8);
    *(bf16x8*)&Bs[br][bc + 16] = *(const bf16x8*)(pp + 16);
    *(bf16x8*)&Bs[br][bc + 24] = *(const bf16x8*)(pp + 24);
    __syncthreads();
#pragma unroll
    for (int kk = 0; kk < 64; kk += 32) {
      bf16x8 a0 = ldsfrag(&As[wm][kk]);
      bf16x8 a1 = ldsfrag(&As[wm + 16][kk]);
#pragma unroll
      for (int n = 0; n < 4; ++n) {
        bf16x8 bb = ldsfrag(&Bs[wn + n * 16][kk]);
        acc[0][n] = MFMA16(a0, bb, acc[0][n]);
        acc[1][n] = MFMA16(a1, bb, acc[1][n]);
      }
    }
    __syncthreads();
  }
  const int cc = lane & 15, rr = (lane >> 4) * 4;
#pragma unroll
  for (int m = 0; m < 2; ++m)
#pragma unroll
    for (int n = 0; n < 4; ++n)
#pragma unroll
      for (int j = 0; j < 4; ++j)
        L[(long)(m0 + wm + m * 16 + rr + j) * 128 + wn + n * 16 + cc] = acc[m][n][j];
}

// ---------------------------------------------------------------------------
// dispatch softmax over tokens (axis N): partial + final stats (fp32)
// ---------------------------------------------------------------------------
__global__ __launch_bounds__(256) void disp_partial(const float* __restrict__ L,
    float* __restrict__ redM, float* __restrict__ redS)
{
  const int chunk = blockIdx.x;      // 0..31
  const int b     = blockIdx.y;      // 0..7
  const int t    = threadIdx.x & 127;
  const int half = threadIdx.x >> 7;
  const float* Lb = L + (long)b * N_ * T_;
  float m = -1e30f, s = 0.f;
  for (int i = 0; i < 64; ++i) {
    int n = chunk * 128 + i * 2 + half;
    float v = Lb[(long)n * T_ + t];
    if (v > m) { s = s * expf(m - v) + 1.f; m = v; }
    else       { s += expf(v - m); }
  }
  __shared__ float sm[128], ss[128];
  if (half) { sm[t] = m; ss[t] = s; }
  __syncthreads();
  if (!half) {
    float m2 = sm[t], s2 = ss[t];
    float nm = fmaxf(m, m2);
    float ns = s * expf(m - nm) + s2 * expf(m2 - nm);
    redM[((long)b * 32 + chunk) * 128 + t] = nm;
    redS[((long)b * 32 + chunk) * 128 + t] = ns;
  }
}

__global__ void disp_final(const float* __restrict__ redM, const float* __restrict__ redS,
                           float* __restrict__ Mf, float* __restrict__ Zf)
{
  int idx = blockIdx.x * 256 + threadIdx.x;   // 1024 total
  int b = idx >> 7, t = idx & 127;
  float m = -1e30f, s = 0.f;
  for (int c = 0; c < 32; ++c) {
    float mc = redM[((long)b * 32 + c) * 128 + t];
    float sc = redS[((long)b * 32 + c) * 128 + t];
    float nm = fmaxf(m, mc);
    s = s * expf(m - nm) + sc * expf(mc - nm);
    m = nm;
  }
  Mf[idx] = m;
  Zf[idx] = 1.f / s;
}

// ---------------------------------------------------------------------------
// dispatch weights, TRANSPOSED + bf16: DWT[b][t][n] = softmax_n(logits)[n][t]
// block: 64 n-rows x 128 t, LDS fp32 transpose
// ---------------------------------------------------------------------------
__global__ __launch_bounds__(256) void k_dwt(const float* __restrict__ L,
    const float* __restrict__ Mf, const float* __restrict__ Zf, bf16* __restrict__ DWT)
{
  __shared__ float S[64][132];
  const int b = blockIdx.y, n0 = blockIdx.x * 64;
  const int tid = threadIdx.x;
  const int r = tid >> 2;            // n-row 0..63
  const int c0 = (tid & 3) * 32;     // t col base
  const float* Lp = L + ((long)b * N_ + n0 + r) * T_ + c0;
#pragma unroll
  for (int i = 0; i < 32; i += 4) {
    float4 v = *(const float4*)(Lp + i);
    int tb = b * 128 + c0 + i;
    S[r][c0 + i + 0] = expf(v.x - Mf[tb + 0]) * Zf[tb + 0];
    S[r][c0 + i + 1] = expf(v.y - Mf[tb + 1]) * Zf[tb + 1];
    S[r][c0 + i + 2] = expf(v.z - Mf[tb + 2]) * Zf[tb + 2];
    S[r][c0 + i + 3] = expf(v.w - Mf[tb + 3]) * Zf[tb + 3];
  }
  __syncthreads();
  const int nc = (tid & 7) * 8;
  for (int ti = tid >> 3; ti < 128; ti += 32) {
    bf16x8 o;
#pragma unroll
    for (int j = 0; j < 8; ++j) o[j] = (bf16)S[nc + j][ti];
    *(bf16x8*)(DWT + ((long)b * 128 + ti) * 4096 + n0 + nc) = o;
  }
}

// combine softmax over slots (axis T=128) -> bf16 CW
__global__ __launch_bounds__(256) void k_cw(const float* __restrict__ L, bf16* __restrict__ CW)
{
  const int row  = blockIdx.x * 4 + (threadIdx.x >> 6);   // B*N rows
  const int lane = threadIdx.x & 63;
  const float* Lr = L + (long)row * T_;
  float v0 = Lr[lane], v1 = Lr[lane + 64];
  float m = fmaxf(v0, v1);
#pragma unroll
  for (int o = 32; o; o >>= 1) m = fmaxf(m, __shfl_xor(m, o));
  float e0 = expf(v0 - m), e1 = expf(v1 - m);
  float s = e0 + e1;
#pragma unroll
  for (int o = 32; o; o >>= 1) s += __shfl_xor(s, o);
  float inv = 1.f / s;
  CW[(long)row * T_ + lane]      = (bf16)(e0 * inv);
  CW[(long)row * T_ + lane + 64] = (bf16)(e1 * inv);
}

// ---------------------------------------------------------------------------
// slots: Part[chunk][b][t][d] = sum_{n in chunk} DWT[b][t][n] * Xbf[b][n][d]
// per b: M=128(t), N=1024(d), K=4096(n) split 8; BM=128, BN=128, BK=64
// ---------------------------------------------------------------------------
__global__ __launch_bounds__(256) void k_slots(
    const bf16* __restrict__ DWT, const bf16* __restrict__ Xbf, float* __restrict__ Part)
{
  __shared__ bf16 As[128][LDK];    // [t][n]
  __shared__ bf16 Bs[128][LDK];    // [d][n] (transposed staging)
  const int b = blockIdx.z >> 3, chunk = blockIdx.z & 7;
  const int d0 = blockIdx.x * 128;
  const int tid = threadIdx.x, wave = tid >> 6, lane = tid & 63;
  const int wm = (wave >> 1) * 64, wn = (wave & 1) * 64;

  f32x4 acc[4][4];
#pragma unroll
  for (int i = 0; i < 4; ++i)
#pragma unroll
    for (int j = 0; j < 4; ++j) acc[i][j] = (f32x4){0.f, 0.f, 0.f, 0.f};

  const int at = tid >> 1, anc = (tid & 1) * 32;
  const int bn = tid >> 2, bdc = (tid & 3) * 32;
  const long dwt_b = (long)b * 128 * 4096;
  const long x_b   = (long)b * 4096 * 1024;

  for (int k0 = 0; k0 < 512; k0 += 64) {
    const int nbase = chunk * 512 + k0;
    const bf16* ap = DWT + dwt_b + (long)at * 4096 + nbase + anc;
    *(bf16x8*)&As[at][anc + 0]  = *(const bf16x8*)(ap + 0);
    *(bf16x8*)&As[at][anc + 8]  = *(const bf16x8*)(ap + 8);
    *(bf16x8*)&As[at][anc + 16] = *(const bf16x8*)(ap + 16);
    *(bf16x8*)&As[at][anc + 24] = *(const bf16x8*)(ap + 24);
    const bf16* xp = Xbf + x_b + (long)(nbase + bn) * 1024 + d0 + bdc;
    bf16x8 q0 = *(const bf16x8*)(xp + 0);
    bf16x8 q1 = *(const bf16x8*)(xp + 8);
    bf16x8 q2 = *(const bf16x8*)(xp + 16);
    bf16x8 q3 = *(const bf16x8*)(xp + 24);
#pragma unroll
    for (int i = 0; i < 8; ++i) {
      Bs[bdc + i][bn]      = q0[i];
      Bs[bdc + 8 + i][bn]  = q1[i];
      Bs[bdc + 16 + i][bn] = q2[i];
      Bs[bdc + 24 + i][bn] = q3[i];
    }
    __syncthreads();
#pragma unroll
    for (int kk = 0; kk < 64; kk += 32) {
      bf16x8 af[4], bfr[4];
#pragma unroll
      for (int m = 0; m < 4; ++m) af[m]  = ldsfrag(&As[wm + m * 16][kk]);
#pragma unroll
      for (int n = 0; n < 4; ++n) bfr[n] = ldsfrag(&Bs[wn + n * 16][kk]);
#pragma unroll
      for (int m = 0; m < 4; ++m)
#pragma unroll
        for (int n = 0; n < 4; ++n)
          acc[m][n] = MFMA16(af[m], bfr[n], acc[m][n]);
    }
    __syncthreads();
  }
  const int cc = lane & 15, rr = (lane >> 4) * 4;
  float* Cp = Part + (long)(chunk * 8 + b) * 128 * 1024;
#pragma unroll
  for (int m = 0; m < 4; ++m)
#pragma unroll
    for (int n = 0; n < 4; ++n)
#pragma unroll
      for (int j = 0; j < 4; ++j)
        Cp[(long)(wm + m * 16 + rr + j) * 1024 + d0 + wn + n * 16 + cc] = acc[m][n][j];
}

__global__ void k_reduce8(const float* __restrict__ P, bf16* __restrict__ O)
{
  long base = ((long)blockIdx.x * 256 + threadIdx.x) * 4;
  float4 s = *(const float4*)(P + base);
  for (int c = 1; c < 8; ++c) {
    float4 v = *(const float4*)(P + (long)c * 1048576 + base);
    s.x += v.x; s.y += v.y; s.z += v.z; s.w += v.w;
  }
  *(bf16x4*)(O + base) = (bf16x4){(bf16)s.x, (bf16)s.y, (bf16)s.z, (bf16)s.w};
}

// ---------------------------------------------------------------------------
// per-expert MLP layer: M=16 rows, N=1024(h) tiled 64, K=1024; weights fp32.
// INL=0: A rows at (b*128 + e*2 + s); INL=1: compact [e*16 + m]. Out uses !INL.
// ---------------------------------------------------------------------------
template<int GELU, int INL>
__global__ __launch_bounds__(256) void k_expert(
    const bf16* __restrict__ Ab, const float* __restrict__ W,
    const float* __restrict__ bias, bf16* __restrict__ Out)
{
  __shared__ bf16 As[16][LDK];
  __shared__ bf16 Bs[64][LDK];
  const int e = blockIdx.y;
  const int h0 = blockIdx.x * 64;
  const int tid = threadIdx.x, wave = tid >> 6, lane = tid & 63;
  f32x4 acc = (f32x4){0.f, 0.f, 0.f, 0.f};

  const int hr = tid >> 2, kc = (tid & 3) * 16;

  for (int k0 = 0; k0 < 1024; k0 += 64) {
    if (tid < 128) {
      int r = tid >> 3, akc = (tid & 7) * 8;
      long row = (INL == 0) ? (long)((r >> 1) * 128 + e * 2 + (r & 1)) : (long)(e * 16 + r);
      *(bf16x8*)&As[r][akc] = *(const bf16x8*)(Ab + row * 1024 + k0 + akc);
    }
    const float* wp = W + ((long)e * 1024 + h0 + hr) * 1024 + k0 + kc;
    float4 w0 = *(const float4*)(wp + 0);
    float4 w1 = *(const float4*)(wp + 4);
    float4 w2 = *(const float4*)(wp + 8);
    float4 w3 = *(const float4*)(wp + 12);
    bf16x8 p0 = {(bf16)w0.x, (bf16)w0.y, (bf16)w0.z, (bf16)w0.w,
                 (bf16)w1.x, (bf16)w1.y, (bf16)w1.z, (bf16)w1.w};
    bf16x8 p1 = {(bf16)w2.x, (bf16)w2.y, (bf16)w2.z, (bf16)w2.w,
                 (bf16)w3.x, (bf16)w3.y, (bf16)w3.z, (bf16)w3.w};
    *(bf16x8*)&Bs[hr][kc]     = p0;
    *(bf16x8*)&Bs[hr][kc + 8] = p1;
    __syncthreads();
#pragma unroll
    for (int kk = 0; kk < 64; kk += 32) {
      bf16x8 a  = ldsfrag(&As[0][kk]);
      bf16x8 bb = ldsfrag(&Bs[wave * 16][kk]);
      acc = MFMA16(a, bb, acc);
    }
    __syncthreads();
  }
  const int cc = lane & 15, rr = (lane >> 4) * 4;
  const int h = h0 + wave * 16 + cc;
  const float bs = bias[e * 1024 + h];
#pragma unroll
  for (int j = 0; j < 4; ++j) {
    float v = acc[j] + bs;
    if (GELU) {
      float x3 = v * v * v;
      v = 0.5f * v * (1.f + tanhf(0.7978845608028654f * (v + 0.044715f * x3)));
    }
    int m = rr + j;
    long orow = (INL == 0) ? (long)(e * 16 + m) : (long)((m >> 1) * 128 + e * 2 + (m & 1));
    Out[orow * 1024 + h] = (bf16)v;
  }
}

// ---------------------------------------------------------------------------
// projT[o][bt] = sum_d out_w_bf[o][d] * outs_bf[bt][d]   (1024x1024x1024)
// BM=BN=64, 4 waves (32x32 each)
// ---------------------------------------------------------------------------
__global__ __launch_bounds__(256) void k_proj(
    const bf16* __restrict__ OWbf, const bf16* __restrict__ OS, bf16* __restrict__ PT)
{
  __shared__ bf16 As[64][LDK];
  __shared__ bf16 Bs[64][LDK];
  const int o0 = blockIdx.y * 64, t0 = blockIdx.x * 64;
  const int tid = threadIdx.x, wave = tid >> 6, lane = tid & 63;
  const int wm = (wave >> 1) * 32, wn = (wave & 1) * 32;
  f32x4 acc[2][2];
#pragma unroll
  for (int i = 0; i < 2; ++i)
#pragma unroll
    for (int j = 0; j < 2; ++j) acc[i][j] = (f32x4){0.f, 0.f, 0.f, 0.f};

  const int r = tid >> 2, kc = (tid & 3) * 16;
  for (int k0 = 0; k0 < 1024; k0 += 64) {
    const bf16* apo = OWbf + (long)(o0 + r) * 1024 + k0 + kc;
    *(bf16x8*)&As[r][kc]     = *(const bf16x8*)(apo + 0);
    *(bf16x8*)&As[r][kc + 8] = *(const bf16x8*)(apo + 8);
    const bf16* bpo = OS + (long)(t0 + r) * 1024 + k0 + kc;
    *(bf16x8*)&Bs[r][kc]     = *(const bf16x8*)(bpo + 0);
    *(bf16x8*)&Bs[r][kc + 8] = *(const bf16x8*)(bpo + 8);
    __syncthreads();
#pragma unroll
    for (int kk = 0; kk < 64; kk += 32) {
      bf16x8 a0 = ldsfrag(&As[wm][kk]);
      bf16x8 a1 = ldsfrag(&As[wm + 16][kk]);
      bf16x8 b0 = ldsfrag(&Bs[wn][kk]);
      bf16x8 b1 = ldsfrag(&Bs[wn + 16][kk]);
      acc[0][0] = MFMA16(a0, b0, acc[0][0]);
      acc[0][1] = MFMA16(a0, b1, acc[0][1]);
      acc[1][0] = MFMA16(a1, b0, acc[1][0]);
      acc[1][1] = MFMA16(a1, b1, acc[1][1]);
    }
    __syncthreads();
  }
  const int cc = lane & 15, rr = (lane >> 4) * 4;
#pragma unroll
  for (int m = 0; m < 2; ++m)
#pragma unroll
    for (int n = 0; n < 2; ++n)
#pragma unroll
      for (int j = 0; j < 4; ++j)
        PT[(long)(o0 + wm + m * 16 + rr + j) * 1024 + t0 + wn + n * 16 + cc] =
            (bf16)acc[m][n][j];
}

// ---------------------------------------------------------------------------
// out[b][n][o] = sum_t CW[b][n][t] * PT[o][b*128+t] + out_b[o]
// per b: M=4096, N=1024, K=128; BM=128, BN=128, BK=64
// ---------------------------------------------------------------------------
__global__ __launch_bounds__(256) void k_combine(
    const bf16* __restrict__ CW, const bf16* __restrict__ PT,
    const float* __restrict__ ob, float* __restrict__ O)
{
  __shared__ bf16 As[128][LDK];
  __shared__ bf16 Bs[128][LDK];
  const int b = blockIdx.z, m0 = blockIdx.y * 128, o0 = blockIdx.x * 128;
  const int tid = threadIdx.x, wave = tid >> 6, lane = tid & 63;
  const int wm = (wave >> 1) * 64, wn = (wave & 1) * 64;

  f32x4 acc[4][4];
#pragma unroll
  for (int i = 0; i < 4; ++i)
#pragma unroll
    for (int j = 0; j < 4; ++j) acc[i][j] = (f32x4){0.f, 0.f, 0.f, 0.f};

  const int r = tid >> 1, tc = (tid & 1) * 32;
  for (int k0 = 0; k0 < 128; k0 += 64) {
    const bf16* ap = CW + ((long)b * N_ + m0 + r) * 128 + k0 + tc;
    *(bf16x8*)&As[r][tc + 0]  = *(const bf16x8*)(ap + 0);
    *(bf16x8*)&As[r][tc + 8]  = *(const bf16x8*)(ap + 8);
    *(bf16x8*)&As[r][tc + 16] = *(const bf16x8*)(ap + 16);
    *(bf16x8*)&As[r][tc + 24] = *(const bf16x8*)(ap + 24);
    const bf16* bp = PT + (long)(o0 + r) * 1024 + b * 128 + k0 + tc;
    *(bf16x8*)&Bs[r][tc + 0]  = *(const bf16x8*)(bp + 0);
    *(bf16x8*)&Bs[r][tc + 8]  = *(const bf16x8*)(bp + 8);
    *(bf16x8*)&Bs[r][tc + 16] = *(const bf16x8*)(bp + 16);
    *(bf16x8*)&Bs[r][tc + 24] = *(const bf16x8*)(bp + 24);
    __syncthreads();
#pragma unroll
    for (int kk = 0; kk < 64; kk += 32) {
      bf16x8 af[4], bfr[4];
#pragma unroll
      for (int m = 0; m < 4; ++m) af[m]  = ldsfrag(&As[wm + m * 16][kk]);
#pragma unroll
      for (int n = 0; n < 4; ++n) bfr[n] = ldsfrag(&Bs[wn + n * 16][kk]);
#pragma unroll
      for (int m = 0; m < 4; ++m)
#pragma unroll
        for (int n = 0; n < 4; ++n)
          acc[m][n] = MFMA16(af[m], bfr[n], acc[m][n]);
    }
    __syncthreads();
  }
  const int cc = lane & 15, rr = (lane >> 4) * 4;
#pragma unroll
  for (int n = 0; n < 4; ++n) {
    const int o = o0 + wn + n * 16 + cc;
    const float bv = ob[o];
#pragma unroll
    for (int m = 0; m < 4; ++m)
#pragma unroll
      for (int j = 0; j < 4; ++j)
        O[((long)b * N_ + m0 + wm + m * 16 + rr + j) * 1024 + o] = acc[m][n][j] + bv;
  }
}

__global__ void write_aux(float* __restrict__ out) { out[(long)B_ * N_ * D_] = 0.f; }

// ---------------------------------------------------------------------------
extern "C" void kernel_launch(void* const* d_in, const int* in_sizes, int n_in,
                              void* d_out, int out_size, void* d_ws, size_t ws_size,
                              hipStream_t stream)
{
  const float* x     = (const float*)d_in[0];
  const float* phi_w = (const float*)d_in[1];
  const float* fc1_w = (const float*)d_in[2];
  const float* fc1_b = (const float*)d_in[3];
  const float* fc2_w = (const float*)d_in[4];
  const float* fc2_b = (const float*)d_in[5];
  const float* out_w = (const float*)d_in[6];
  const float* out_b = (const float*)d_in[7];
  float* out = (float*)d_out;

  float* ws     = (float*)d_ws;
  float* logits = ws;                         // 4,194,304 f
  float* redM   = logits + 4194304;           // 32,768
  float* redS   = redM + 32768;               // 32,768
  float* Mf     = redS + 32768;               // 1,024
  float* Zf     = Mf + 1024;                  // 1,024
  bf16* DWT     = (bf16*)(Zf + 1024);         // 4,194,304 bf16
  bf16* CW      = DWT + 4194304;              // 4,194,304 bf16
  bf16* slots   = CW + 4194304;               // 1,048,576 bf16
  bf16* hbuf    = slots + 1048576;            // 1,048,576 bf16
  bf16* outs    = hbuf + 1048576;             // 1,048,576 bf16
  bf16* projT   = outs + 1048576;             // 1,048,576 bf16
  bf16* phi_bf  = projT + 1048576;            // 131,072 bf16
  bf16* outw_bf = phi_bf + 131072;            // 1,048,576 bf16  (~44.4 MB total)

  // scratch in d_out (dead before k_combine writes it):
  bf16* Xbf   = (bf16*)d_out;                 // 33,554,432 bf16 = 64 MB
  float* Part = (float*)d_out + 16777216;     // 8 x 1,048,576 f = 32 MB

  k_convert<<<dim3(1152), 256, 0, stream>>>(phi_w, out_w, phi_bf, outw_bf);
  k_logits<<<dim3(512), 256, 0, stream>>>(x, phi_bf, logits, Xbf);
  disp_partial<<<dim3(32, 8), 256, 0, stream>>>(logits, redM, redS);
  disp_final<<<dim3(4), 256, 0, stream>>>(redM, redS, Mf, Zf);
  k_dwt<<<dim3(64, 8), 256, 0, stream>>>(logits, Mf, Zf, DWT);
  k_cw<<<dim3(8192), 256, 0, stream>>>(logits, CW);
  k_slots<<<dim3(8, 1, 64), 256, 0, stream>>>(DWT, Xbf, Part);
  k_reduce8<<<dim3(1024), 256, 0, stream>>>(Part, slots);
  k_expert<1, 0><<<dim3(16, 64), 256, 0, stream>>>(slots, fc1_w, fc1_b, hbuf);
  k_expert<0, 1><<<dim3(16, 64), 256, 0, stream>>>(hbuf, fc2_w, fc2_b, outs);
  k_proj<<<dim3(16, 16), 256, 0, stream>>>(outw_bf, outs, projT);
  k_combine<<<dim3(8, 32, 8), 256, 0, stream>>>(CW, projT, out_b, out);
  write_aux<<<1, 1, 0, stream>>>(out);
}